// Round 1
// baseline (273.123 us; speedup 1.0000x reference)
//
#include <hip/hip_runtime.h>

typedef unsigned short u16;
typedef __attribute__((ext_vector_type(8))) __bf16 bf16x8;
typedef __attribute__((ext_vector_type(4))) float f32x4;
typedef __attribute__((ext_vector_type(4))) unsigned int u32x4;

#define MFMA16(a, b, c) __builtin_amdgcn_mfma_f32_16x16x32_bf16((a), (b), (c), 0, 0, 0)

__device__ __forceinline__ u16 f2bf(float f) {
  unsigned u = __float_as_uint(f);
  u += 0x7FFFu + ((u >> 16) & 1u);
  return (u16)(u >> 16);
}

// ---------------- weight transpose+convert: W[K][N] f32 -> Wt[N][K] bf16 ----------------
__global__ __launch_bounds__(256) void wt_kernel(const float* __restrict__ W, u16* __restrict__ Wt,
                                                 int K, int N) {
  __shared__ float tile[64][65];
  int ntn = N >> 6;
  int kt = blockIdx.x / ntn, nt = blockIdx.x % ntn;
  int t = threadIdx.x;
  const float* src = W + (size_t)kt * 64 * N + (size_t)nt * 64;
#pragma unroll
  for (int i = 0; i < 16; ++i) {
    int idx = t + i * 256, kk = idx >> 6, nn = idx & 63;
    tile[kk][nn] = src[(size_t)kk * N + nn];
  }
  __syncthreads();
  u16* dst = Wt + (size_t)nt * 64 * K + (size_t)kt * 64;
#pragma unroll
  for (int i = 0; i < 16; ++i) {
    int idx = t + i * 256, nn = idx >> 6, kk = idx & 63;
    dst[(size_t)nn * K + kk] = f2bf(tile[kk][nn]);
  }
}

// ---------------- W_rk/W_rv -> Wt[c'][f] with f = r*64+c  (k = c*4+r) ----------------
__global__ __launch_bounds__(256) void wperm_kernel(const float* __restrict__ Wrk,
                                                    const float* __restrict__ Wrv,
                                                    u16* __restrict__ Wtk, u16* __restrict__ Wtv) {
  int idx = blockIdx.x * 256 + threadIdx.x;  // 16384 = 64 c' * 256 f
  int cp = idx >> 8, f = idx & 255;
  int k = ((f & 63) << 2) | (f >> 6);
  Wtk[idx] = f2bf(Wrk[k * 64 + cp]);
  Wtv[idx] = f2bf(Wrv[k * 64 + cp]);
}

// ---------------- LN1 over channels; emit xf[p][c] and xfT[c][p] (bf16) ----------------
__global__ __launch_bounds__(256) void ln1_kernel(const float* __restrict__ x,
                                                  const float* __restrict__ w,
                                                  const float* __restrict__ bias,
                                                  u16* __restrict__ xf_pc, u16* __restrict__ xfT) {
  __shared__ float tile[64 * 65];
  int b = blockIdx.x >> 6, p0 = (blockIdx.x & 63) << 6;
  int t = threadIdx.x;
  const float* xb = x + (size_t)b * 64 * 4096;
#pragma unroll
  for (int i = 0; i < 16; ++i) {
    int idx = t + i * 256, c = idx >> 6, p = idx & 63;
    tile[c * 65 + p] = xb[(size_t)c * 4096 + p0 + p];
  }
  __syncthreads();
  int lane = t & 63, wv = t >> 6;
  float gw = w[lane], gb = bias[lane];
  for (int pi = 0; pi < 16; ++pi) {
    int p = wv * 16 + pi;
    float v = tile[lane * 65 + p];
    float s = v, s2 = v * v;
#pragma unroll
    for (int m = 1; m < 64; m <<= 1) { s += __shfl_xor(s, m); s2 += __shfl_xor(s2, m); }
    float mean = s * (1.0f / 64.0f);
    float var = s2 * (1.0f / 64.0f) - mean * mean;
    float y = (v - mean) * rsqrtf(var + 1e-5f) * gw + gb;
    tile[lane * 65 + p] = y;
  }
  __syncthreads();
  u16* xfb = xf_pc + (size_t)b * 4096 * 64;
  u16* xtb = xfT + (size_t)b * 64 * 4096;
#pragma unroll
  for (int i = 0; i < 16; ++i) {
    int idx = t + i * 256;
    int p1 = idx >> 6, c1 = idx & 63;
    xfb[(size_t)(p0 + p1) * 64 + c1] = f2bf(tile[c1 * 65 + p1]);
    int c2 = idx >> 6, p2 = idx & 63;
    xtb[(size_t)c2 * 4096 + p0 + p2] = f2bf(tile[c2 * 65 + p2]);
  }
}

// ---------------- KV spatial reduction GEMM (64x64x256) + LN2 + transposed store ----------------
__global__ __launch_bounds__(256) void kv_kernel(const u16* __restrict__ xf_pc,
                                                 const u16* __restrict__ Wtk, const u16* __restrict__ Wtv,
                                                 const float* __restrict__ ln2w, const float* __restrict__ ln2b,
                                                 u16* __restrict__ kT, u16* __restrict__ vT) {
  __shared__ u16 As[64 * 264];
  __shared__ u16 Bk[64 * 264];
  __shared__ u16 Bv[64 * 264];
  u16* Tk = As;            // reuse As after compute (needs 64*72)
  u16* Tv = As + 64 * 72;  // 2*64*72 = 9216 <= 64*264
  int b = blockIdx.x >> 4, s0 = (blockIdx.x & 15) << 6;
  int t = threadIdx.x;
  const u16* Asrc = xf_pc + (size_t)b * 4096 * 64 + (size_t)s0 * 256;
#pragma unroll
  for (int i = 0; i < 8; ++i) {
    int id = t + i * 256, row = id >> 5, c16 = id & 31;
    *(u32x4*)&As[row * 264 + c16 * 8] = *(const u32x4*)&Asrc[(size_t)row * 256 + c16 * 8];
    *(u32x4*)&Bk[row * 264 + c16 * 8] = *(const u32x4*)&Wtk[(size_t)row * 256 + c16 * 8];
    *(u32x4*)&Bv[row * 264 + c16 * 8] = *(const u32x4*)&Wtv[(size_t)row * 256 + c16 * 8];
  }
  __syncthreads();
  int lane = t & 63, wv = t >> 6, lo = lane & 15, hi = lane >> 4;
  f32x4 acck[4] = {}, accv[4] = {};
  int arow = (wv * 16 + lo) * 264 + hi * 8;
#pragma unroll
  for (int kk = 0; kk < 8; ++kk) {
    bf16x8 a = *(const bf16x8*)&As[arow + kk * 32];
#pragma unroll
    for (int nf = 0; nf < 4; ++nf) {
      bf16x8 bk = *(const bf16x8*)&Bk[(nf * 16 + lo) * 264 + kk * 32 + hi * 8];
      bf16x8 bv = *(const bf16x8*)&Bv[(nf * 16 + lo) * 264 + kk * 32 + hi * 8];
      acck[nf] = MFMA16(a, bk, acck[nf]);
      accv[nf] = MFMA16(a, bv, accv[nf]);
    }
  }
  __syncthreads();  // done reading As; Tk/Tv alias it
  float w2[4], b2[4];
#pragma unroll
  for (int nf = 0; nf < 4; ++nf) { w2[nf] = ln2w[nf * 16 + lo]; b2[nf] = ln2b[nf * 16 + lo]; }
#pragma unroll
  for (int r = 0; r < 4; ++r) {
    float sk = 0.f, sk2 = 0.f, sv = 0.f, sv2 = 0.f;
#pragma unroll
    for (int nf = 0; nf < 4; ++nf) {
      float a = acck[nf][r], c = accv[nf][r];
      sk += a; sk2 += a * a; sv += c; sv2 += c * c;
    }
#pragma unroll
    for (int m = 1; m < 16; m <<= 1) {
      sk += __shfl_xor(sk, m); sk2 += __shfl_xor(sk2, m);
      sv += __shfl_xor(sv, m); sv2 += __shfl_xor(sv2, m);
    }
    float mk = sk * (1.f / 64.f), vk = sk2 * (1.f / 64.f) - mk * mk, rk = rsqrtf(vk + 1e-5f);
    float mv = sv * (1.f / 64.f), vv = sv2 * (1.f / 64.f) - mv * mv, rv = rsqrtf(vv + 1e-5f);
    int srow = wv * 16 + hi * 4 + r;
#pragma unroll
    for (int nf = 0; nf < 4; ++nf) {
      Tk[(nf * 16 + lo) * 72 + srow] = f2bf((acck[nf][r] - mk) * rk * w2[nf] + b2[nf]);
      Tv[(nf * 16 + lo) * 72 + srow] = f2bf((accv[nf][r] - mv) * rv * w2[nf] + b2[nf]);
    }
  }
  __syncthreads();
  u16* kdst = kT + (size_t)b * 64 * 1024 + s0;
  u16* vdst = vT + (size_t)b * 64 * 1024 + s0;
#pragma unroll
  for (int i = 0; i < 16; ++i) {
    int idx = t + i * 256, cp = idx >> 6, s = idx & 63;
    kdst[(size_t)cp * 1024 + s] = Tk[cp * 72 + s];
    vdst[(size_t)cp * 1024 + s] = Tv[cp * 72 + s];
  }
}

// ---------------- generic GEMM: C[m][n] = sum_k A[m][k]*B[n][k], bf16 in, tile 128x128x64 ----------------
// EPI 0: bf16 store C[m*N+n]
// EPI 1: bf16 store C[(n>>6)*chunk + m*64 + (n&63)]   (batch-split columns)
// EPI 2: f32 store C[m*N+n] = acc + resid[m*N+n]
template <int EPI>
__global__ __launch_bounds__(256) void gemm_kernel(const u16* __restrict__ A, const u16* __restrict__ Bm,
                                                   void* __restrict__ Cc, const float* __restrict__ resid,
                                                   int M, int N, int K, int chunkStride) {
  __shared__ u16 As[128 * 72];
  __shared__ u16 Bs[128 * 72];
  int ntn = N >> 7;
  int mt = blockIdx.x / ntn, nt = blockIdx.x % ntn;
  int t = threadIdx.x, lane = t & 63, wv = t >> 6;
  int wm = (wv >> 1) * 64, wn = (wv & 1) * 64;
  int lo = lane & 15, hi = lane >> 4;
  f32x4 acc[4][4] = {};
  const u16* Ab = A + (size_t)mt * 128 * K;
  const u16* Bb = Bm + (size_t)nt * 128 * K;
  int nk = K >> 6;
  for (int kt = 0; kt < nk; ++kt) {
    __syncthreads();
#pragma unroll
    for (int i = 0; i < 4; ++i) {
      int id = t + i * 256, row = id >> 3, c16 = id & 7;
      *(u32x4*)&As[row * 72 + c16 * 8] = *(const u32x4*)&Ab[(size_t)row * K + kt * 64 + c16 * 8];
      *(u32x4*)&Bs[row * 72 + c16 * 8] = *(const u32x4*)&Bb[(size_t)row * K + kt * 64 + c16 * 8];
    }
    __syncthreads();
#pragma unroll
    for (int kk = 0; kk < 2; ++kk) {
      bf16x8 a[4], bb[4];
#pragma unroll
      for (int i = 0; i < 4; ++i) {
        a[i]  = *(const bf16x8*)&As[(wm + i * 16 + lo) * 72 + kk * 32 + hi * 8];
        bb[i] = *(const bf16x8*)&Bs[(wn + i * 16 + lo) * 72 + kk * 32 + hi * 8];
      }
#pragma unroll
      for (int mi = 0; mi < 4; ++mi)
#pragma unroll
        for (int ni = 0; ni < 4; ++ni)
          acc[mi][ni] = MFMA16(a[mi], bb[ni], acc[mi][ni]);
    }
  }
#pragma unroll
  for (int mi = 0; mi < 4; ++mi)
#pragma unroll
    for (int ni = 0; ni < 4; ++ni)
#pragma unroll
      for (int r = 0; r < 4; ++r) {
        int m = mt * 128 + wm + mi * 16 + hi * 4 + r;
        int n = nt * 128 + wn + ni * 16 + lo;
        float v = acc[mi][ni][r];
        if constexpr (EPI == 0) {
          ((u16*)Cc)[(size_t)m * N + n] = f2bf(v);
        } else if constexpr (EPI == 1) {
          ((u16*)Cc)[(size_t)(n >> 6) * chunkStride + (size_t)m * 64 + (n & 63)] = f2bf(v);
        } else {
          size_t ad = (size_t)m * N + n;
          ((float*)Cc)[ad] = v + resid[ad];
        }
      }
}

// ---------------- attention: per (b, head, 128-row q tile); full K (128) per block ----------------
__global__ __launch_bounds__(256) void attn_kernel(const u16* __restrict__ q, const u16* __restrict__ kp,
                                                   const u16* __restrict__ vp, u16* __restrict__ o2) {
  __shared__ u16 Qs[128 * 72];
  __shared__ u16 Ks[128 * 72];
  __shared__ u16 Vs[64 * 136];
  __shared__ u16 Ps[128 * 136];
  int qt = blockIdx.x & 3, h = (blockIdx.x >> 2) & 7, b = blockIdx.x >> 5;
  int t = threadIdx.x, lane = t & 63, wv = t >> 6;
  int lo = lane & 15, hi = lane >> 4;
  const u16* qsrc = q + (size_t)b * 4096 * 64 + (size_t)(h * 512 + qt * 128) * 64;
  const u16* ksrc = kp + (size_t)b * 1024 * 64 + (size_t)(h * 128) * 64;
  const u16* vsrc = vp + (size_t)b * 64 * 1024 + h * 128;
#pragma unroll
  for (int i = 0; i < 4; ++i) {
    int id = t + i * 256;
    int row = id >> 3, c16 = id & 7;
    *(u32x4*)&Qs[row * 72 + c16 * 8] = *(const u32x4*)&qsrc[(size_t)row * 64 + c16 * 8];
    *(u32x4*)&Ks[row * 72 + c16 * 8] = *(const u32x4*)&ksrc[(size_t)row * 64 + c16 * 8];
    int vrow = id >> 4, v16 = id & 15;
    *(u32x4*)&Vs[vrow * 136 + v16 * 8] = *(const u32x4*)&vsrc[(size_t)vrow * 1024 + v16 * 8];
  }
  __syncthreads();
  // S = Q K^T : each wave owns 32 q-rows x 128 k-cols
  f32x4 s[2][8] = {};
#pragma unroll
  for (int kk = 0; kk < 2; ++kk) {
    bf16x8 a0 = *(const bf16x8*)&Qs[(wv * 32 + lo) * 72 + kk * 32 + hi * 8];
    bf16x8 a1 = *(const bf16x8*)&Qs[(wv * 32 + 16 + lo) * 72 + kk * 32 + hi * 8];
#pragma unroll
    for (int ni = 0; ni < 8; ++ni) {
      bf16x8 bb = *(const bf16x8*)&Ks[(ni * 16 + lo) * 72 + kk * 32 + hi * 8];
      s[0][ni] = MFMA16(a0, bb, s[0][ni]);
      s[1][ni] = MFMA16(a1, bb, s[1][ni]);
    }
  }
  const float inv_scale = 0.044194173824159216f;  // 1/sqrt(512)
#pragma unroll
  for (int mi = 0; mi < 2; ++mi)
#pragma unroll
    for (int ni = 0; ni < 8; ++ni) s[mi][ni] *= inv_scale;
#pragma unroll
  for (int mi = 0; mi < 2; ++mi) {
#pragma unroll
    for (int r = 0; r < 4; ++r) {
      float mx = -1e30f;
#pragma unroll
      for (int ni = 0; ni < 8; ++ni) mx = fmaxf(mx, s[mi][ni][r]);
#pragma unroll
      for (int m = 1; m < 16; m <<= 1) mx = fmaxf(mx, __shfl_xor(mx, m));
      float p[8], sum = 0.f;
#pragma unroll
      for (int ni = 0; ni < 8; ++ni) { p[ni] = __expf(s[mi][ni][r] - mx); sum += p[ni]; }
#pragma unroll
      for (int m = 1; m < 16; m <<= 1) sum += __shfl_xor(sum, m);
      float rs = 1.0f / sum;
      int row = wv * 32 + mi * 16 + hi * 4 + r;
#pragma unroll
      for (int ni = 0; ni < 8; ++ni) Ps[row * 136 + ni * 16 + lo] = f2bf(p[ni] * rs);
    }
  }
  __syncthreads();
  // O^T[c][lq] = sum_lk V[c][lk] * P[lq][lk] : each wave owns 64 c-rows x 32 lq-cols
  f32x4 o[4][2] = {};
#pragma unroll
  for (int kk = 0; kk < 4; ++kk) {
    bf16x8 b0 = *(const bf16x8*)&Ps[(wv * 32 + lo) * 136 + kk * 32 + hi * 8];
    bf16x8 b1 = *(const bf16x8*)&Ps[(wv * 32 + 16 + lo) * 136 + kk * 32 + hi * 8];
#pragma unroll
    for (int mi = 0; mi < 4; ++mi) {
      bf16x8 a = *(const bf16x8*)&Vs[(mi * 16 + lo) * 136 + kk * 32 + hi * 8];
      o[mi][0] = MFMA16(a, b0, o[mi][0]);
      o[mi][1] = MFMA16(a, b1, o[mi][1]);
    }
  }
  u16* od = o2 + (size_t)b * 64 * 4096 + h * 512 + qt * 128;
#pragma unroll
  for (int mi = 0; mi < 4; ++mi)
#pragma unroll
    for (int ni = 0; ni < 2; ++ni)
#pragma unroll
      for (int r = 0; r < 4; ++r) {
        int c = mi * 16 + hi * 4 + r;
        int lq = wv * 32 + ni * 16 + lo;
        od[(size_t)c * 4096 + lq] = f2bf(o[mi][ni][r]);
      }
}

extern "C" void kernel_launch(void* const* d_in, const int* in_sizes, int n_in,
                              void* d_out, int out_size, void* d_ws, size_t ws_size,
                              hipStream_t stream) {
  (void)in_sizes; (void)n_in; (void)out_size; (void)ws_size;
  const float* x    = (const float*)d_in[0];
  const float* ln1w = (const float*)d_in[1];
  const float* ln1b = (const float*)d_in[2];
  const float* ln2w = (const float*)d_in[3];
  const float* ln2b = (const float*)d_in[4];
  const float* W_rk = (const float*)d_in[5];
  const float* W_rv = (const float*)d_in[6];
  const float* W_q  = (const float*)d_in[7];
  const float* W_k  = (const float*)d_in[8];
  const float* W_v  = (const float*)d_in[9];
  const float* W_o  = (const float*)d_in[10];

  char* ws = (char*)d_ws;
  size_t off = 0;
  auto alloc = [&](size_t bytes) { char* p = ws + off; off += bytes; return p; };
  u16* Wt_q  = (u16*)alloc(4096ull * 4096 * 2);
  u16* Wt_o  = (u16*)alloc(4096ull * 4096 * 2);
  u16* Wt_k  = (u16*)alloc(1024ull * 1024 * 2);
  u16* Wt_v  = (u16*)alloc(1024ull * 1024 * 2);
  u16* Wt_rk = (u16*)alloc(64ull * 256 * 2);
  u16* Wt_rv = (u16*)alloc(64ull * 256 * 2);
  u16* xf_pc = (u16*)alloc(16ull * 4096 * 64 * 2);
  u16* xfT   = (u16*)alloc(16ull * 64 * 4096 * 2);
  u16* k_lnT = (u16*)alloc(16ull * 64 * 1024 * 2);
  u16* v_lnT = (u16*)alloc(16ull * 64 * 1024 * 2);
  u16* q_t   = (u16*)alloc(16ull * 4096 * 64 * 2);
  u16* kproj = (u16*)alloc(16ull * 1024 * 64 * 2);
  u16* vproj = (u16*)alloc(16ull * 64 * 1024 * 2);
  u16* o2    = (u16*)alloc(16ull * 64 * 4096 * 2);

  wt_kernel<<<4096, 256, 0, stream>>>(W_q, Wt_q, 4096, 4096);
  wt_kernel<<<4096, 256, 0, stream>>>(W_o, Wt_o, 4096, 4096);
  wt_kernel<<<256, 256, 0, stream>>>(W_k, Wt_k, 1024, 1024);
  wt_kernel<<<256, 256, 0, stream>>>(W_v, Wt_v, 1024, 1024);
  wperm_kernel<<<64, 256, 0, stream>>>(W_rk, W_rv, Wt_rk, Wt_rv);
  ln1_kernel<<<1024, 256, 0, stream>>>(x, ln1w, ln1b, xf_pc, xfT);
  kv_kernel<<<256, 256, 0, stream>>>(xf_pc, Wt_rk, Wt_rv, ln2w, ln2b, k_lnT, v_lnT);
  // Q:   q_t[b][j][c]   = sum_p  Wt_q[j][p]   * xfT[(b,c)][p]
  gemm_kernel<1><<<256, 256, 0, stream>>>(Wt_q, xfT, q_t, nullptr, 4096, 1024, 4096, 4096 * 64);
  // K:   kproj[b][jk][c] = sum_s Wt_k[jk][s]  * k_lnT[(b,c)][s]
  gemm_kernel<1><<<64, 256, 0, stream>>>(Wt_k, k_lnT, kproj, nullptr, 1024, 1024, 1024, 1024 * 64);
  // V:   vproj[(b,c)][jv] = sum_s v_lnT[(b,c)][s] * Wt_v[jv][s]
  gemm_kernel<0><<<64, 256, 0, stream>>>(v_lnT, Wt_v, vproj, nullptr, 1024, 1024, 1024, 0);
  attn_kernel<<<512, 256, 0, stream>>>(q_t, kproj, vproj, o2);
  // O:   out[(b,c)][j2] = sum_j o2[(b,c)][j] * Wt_o[j2][j] + x
  gemm_kernel<2><<<256, 256, 0, stream>>>(o2, Wt_o, (float*)d_out, x, 1024, 4096, 4096, 0);
}

// Round 2
// 211.009 us; speedup vs baseline: 1.2944x; 1.2944x over previous
//
#include <hip/hip_runtime.h>

typedef unsigned short u16;
typedef __attribute__((ext_vector_type(8))) __bf16 bf16x8;
typedef __attribute__((ext_vector_type(4))) float f32x4;
typedef __attribute__((ext_vector_type(4))) unsigned int u32x4;

#define MFMA16(a, b, c) __builtin_amdgcn_mfma_f32_16x16x32_bf16((a), (b), (c), 0, 0, 0)

__device__ __forceinline__ u16 f2bf(float f) {
  unsigned u = __float_as_uint(f);
  u += 0x7FFFu + ((u >> 16) & 1u);
  return (u16)(u >> 16);
}

typedef __attribute__((address_space(1))) const unsigned char gU8;
typedef __attribute__((address_space(3))) unsigned char sU8;
__device__ __forceinline__ void gload16(const void* g, void* l) {
  __builtin_amdgcn_global_load_lds((gU8*)g, (sU8*)l, 16, 0, 0);
}

// ================= fused pre-pass: weight transposes + wperm + LN1 =================
__device__ __forceinline__ void wt_body(const float* __restrict__ W, u16* __restrict__ Wt,
                                        int K, int N, int bid, float* tile) {
  int ntn = N >> 6;
  int kt = bid / ntn, nt = bid % ntn;
  int t = threadIdx.x;
  const float* src = W + (size_t)kt * 64 * N + (size_t)nt * 64;
#pragma unroll
  for (int i = 0; i < 16; ++i) {
    int idx = t + i * 256, kk = idx >> 6, nn = idx & 63;
    tile[kk * 65 + nn] = src[(size_t)kk * N + nn];
  }
  __syncthreads();
  u16* dst = Wt + (size_t)nt * 64 * K + (size_t)kt * 64;
#pragma unroll
  for (int i = 0; i < 16; ++i) {
    int idx = t + i * 256, nn = idx >> 6, kk = idx & 63;
    dst[(size_t)nn * K + kk] = f2bf(tile[kk * 65 + nn]);
  }
}

__device__ __forceinline__ void wperm_body(const float* __restrict__ Wrk, const float* __restrict__ Wrv,
                                           u16* __restrict__ Wtk, u16* __restrict__ Wtv, int bid) {
  int idx = bid * 256 + threadIdx.x;  // 16384 = 64 c' * 256 f
  int cp = idx >> 8, f = idx & 255;
  int k = ((f & 63) << 2) | (f >> 6);
  Wtk[idx] = f2bf(Wrk[k * 64 + cp]);
  Wtv[idx] = f2bf(Wrv[k * 64 + cp]);
}

__device__ __forceinline__ void ln1_body(const float* __restrict__ x, const float* __restrict__ w,
                                         const float* __restrict__ bias, u16* __restrict__ xf_pc,
                                         u16* __restrict__ xfT, int bid, float* tile) {
  int b = bid >> 6, p0 = (bid & 63) << 6;
  int t = threadIdx.x;
  const float* xb = x + (size_t)b * 64 * 4096;
#pragma unroll
  for (int i = 0; i < 16; ++i) {
    int idx = t + i * 256, c = idx >> 6, p = idx & 63;
    tile[c * 65 + p] = xb[(size_t)c * 4096 + p0 + p];
  }
  __syncthreads();
  int lane = t & 63, wv = t >> 6;
  float gw = w[lane], gb = bias[lane];
  for (int pi = 0; pi < 16; ++pi) {
    int p = wv * 16 + pi;
    float v = tile[lane * 65 + p];
    float s = v, s2 = v * v;
#pragma unroll
    for (int m = 1; m < 64; m <<= 1) { s += __shfl_xor(s, m); s2 += __shfl_xor(s2, m); }
    float mean = s * (1.0f / 64.0f);
    float var = s2 * (1.0f / 64.0f) - mean * mean;
    float y = (v - mean) * rsqrtf(var + 1e-5f) * gw + gb;
    tile[lane * 65 + p] = y;
  }
  __syncthreads();
  u16* xfb = xf_pc + (size_t)b * 4096 * 64;
  u16* xtb = xfT + (size_t)b * 64 * 4096;
#pragma unroll
  for (int i = 0; i < 16; ++i) {
    int idx = t + i * 256;
    int p1 = idx >> 6, c1 = idx & 63;
    xfb[(size_t)(p0 + p1) * 64 + c1] = f2bf(tile[c1 * 65 + p1]);
    int c2 = idx >> 6, p2 = idx & 63;
    xtb[(size_t)c2 * 4096 + p0 + p2] = f2bf(tile[c2 * 65 + p2]);
  }
}

__global__ __launch_bounds__(256) void prep_kernel(
    const float* __restrict__ W_q, u16* __restrict__ Wt_q,
    const float* __restrict__ W_o, u16* __restrict__ Wt_o,
    const float* __restrict__ W_k, u16* __restrict__ Wt_k,
    const float* __restrict__ W_v, u16* __restrict__ Wt_v,
    const float* __restrict__ W_rk, const float* __restrict__ W_rv,
    u16* __restrict__ Wt_rk, u16* __restrict__ Wt_rv,
    const float* __restrict__ x, const float* __restrict__ ln1w, const float* __restrict__ ln1b,
    u16* __restrict__ xf_pc, u16* __restrict__ xfT) {
  __shared__ float tile[64 * 65];
  int bid = blockIdx.x;
  if (bid < 4096)       wt_body(W_q, Wt_q, 4096, 4096, bid, tile);
  else if (bid < 8192)  wt_body(W_o, Wt_o, 4096, 4096, bid - 4096, tile);
  else if (bid < 8448)  wt_body(W_k, Wt_k, 1024, 1024, bid - 8192, tile);
  else if (bid < 8704)  wt_body(W_v, Wt_v, 1024, 1024, bid - 8448, tile);
  else if (bid < 8768)  wperm_body(W_rk, W_rv, Wt_rk, Wt_rv, bid - 8704);
  else                  ln1_body(x, ln1w, ln1b, xf_pc, xfT, bid - 8768, tile);
}

// ================= KV spatial reduction GEMM (64x64x256) + LN2 + transposed store =================
__global__ __launch_bounds__(256) void kv_kernel(const u16* __restrict__ xf_pc,
                                                 const u16* __restrict__ Wtk, const u16* __restrict__ Wtv,
                                                 const float* __restrict__ ln2w, const float* __restrict__ ln2b,
                                                 u16* __restrict__ kT, u16* __restrict__ vT) {
  __shared__ __align__(16) u16 As[64 * 264];
  __shared__ __align__(16) u16 Bk[64 * 264];
  __shared__ __align__(16) u16 Bv[64 * 264];
  u16* Tk = As;            // reuse As after compute (needs 64*72)
  u16* Tv = As + 64 * 72;  // 2*64*72 = 9216 <= 64*264
  int b = blockIdx.x >> 4, s0 = (blockIdx.x & 15) << 6;
  int t = threadIdx.x;
  const u16* Asrc = xf_pc + (size_t)b * 4096 * 64 + (size_t)s0 * 256;
#pragma unroll
  for (int i = 0; i < 8; ++i) {
    int id = t + i * 256, row = id >> 5, c16 = id & 31;
    *(u32x4*)&As[row * 264 + c16 * 8] = *(const u32x4*)&Asrc[(size_t)row * 256 + c16 * 8];
    *(u32x4*)&Bk[row * 264 + c16 * 8] = *(const u32x4*)&Wtk[(size_t)row * 256 + c16 * 8];
    *(u32x4*)&Bv[row * 264 + c16 * 8] = *(const u32x4*)&Wtv[(size_t)row * 256 + c16 * 8];
  }
  __syncthreads();
  int lane = t & 63, wv = t >> 6, lo = lane & 15, hi = lane >> 4;
  f32x4 acck[4] = {}, accv[4] = {};
  int arow = (wv * 16 + lo) * 264 + hi * 8;
#pragma unroll
  for (int kk = 0; kk < 8; ++kk) {
    bf16x8 a = *(const bf16x8*)&As[arow + kk * 32];
#pragma unroll
    for (int nf = 0; nf < 4; ++nf) {
      bf16x8 bk = *(const bf16x8*)&Bk[(nf * 16 + lo) * 264 + kk * 32 + hi * 8];
      bf16x8 bv = *(const bf16x8*)&Bv[(nf * 16 + lo) * 264 + kk * 32 + hi * 8];
      acck[nf] = MFMA16(a, bk, acck[nf]);
      accv[nf] = MFMA16(a, bv, accv[nf]);
    }
  }
  __syncthreads();  // done reading As; Tk/Tv alias it
  float w2[4], b2[4];
#pragma unroll
  for (int nf = 0; nf < 4; ++nf) { w2[nf] = ln2w[nf * 16 + lo]; b2[nf] = ln2b[nf * 16 + lo]; }
#pragma unroll
  for (int r = 0; r < 4; ++r) {
    float sk = 0.f, sk2 = 0.f, sv = 0.f, sv2 = 0.f;
#pragma unroll
    for (int nf = 0; nf < 4; ++nf) {
      float a = acck[nf][r], c = accv[nf][r];
      sk += a; sk2 += a * a; sv += c; sv2 += c * c;
    }
#pragma unroll
    for (int m = 1; m < 16; m <<= 1) {
      sk += __shfl_xor(sk, m); sk2 += __shfl_xor(sk2, m);
      sv += __shfl_xor(sv, m); sv2 += __shfl_xor(sv2, m);
    }
    float mk = sk * (1.f / 64.f), vk = sk2 * (1.f / 64.f) - mk * mk, rk = rsqrtf(vk + 1e-5f);
    float mv = sv * (1.f / 64.f), vv = sv2 * (1.f / 64.f) - mv * mv, rv = rsqrtf(vv + 1e-5f);
    int srow = wv * 16 + hi * 4 + r;
#pragma unroll
    for (int nf = 0; nf < 4; ++nf) {
      Tk[(nf * 16 + lo) * 72 + srow] = f2bf((acck[nf][r] - mk) * rk * w2[nf] + b2[nf]);
      Tv[(nf * 16 + lo) * 72 + srow] = f2bf((accv[nf][r] - mv) * rv * w2[nf] + b2[nf]);
    }
  }
  __syncthreads();
  u16* kdst = kT + (size_t)b * 64 * 1024 + s0;
  u16* vdst = vT + (size_t)b * 64 * 1024 + s0;
#pragma unroll
  for (int i = 0; i < 16; ++i) {
    int idx = t + i * 256, cp = idx >> 6, s = idx & 63;
    kdst[(size_t)cp * 1024 + s] = Tk[cp * 72 + s];
    vdst[(size_t)cp * 1024 + s] = Tv[cp * 72 + s];
  }
}

// ================= GEMM body: gload_lds staging + double-buffered 2-phase =================
// C[m][n] = sum_k A[m][k]*B[n][k], tile 128x128x64, linear LDS (gload_lds requirement)
__device__ __forceinline__ void stage_tile(const u16* Ab, const u16* Bb, int K, int kt,
                                           u16* As, u16* Bs, int wv, int lane) {
  int gr = lane >> 3;              // row within 8-row chunk
  int gcol = (lane & 7) * 8;       // element col within 64
  const u16* a0 = Ab + (size_t)kt * 64 + gcol;
  const u16* b0 = Bb + (size_t)kt * 64 + gcol;
#pragma unroll
  for (int i = 0; i < 4; ++i) {
    int chunk = wv * 4 + i;
    int row = chunk * 8 + gr;
    gload16(a0 + (size_t)row * K, As + chunk * 512);
    gload16(b0 + (size_t)row * K, Bs + chunk * 512);
  }
}

__device__ __forceinline__ void compute_tile(const u16* As, const u16* Bs, f32x4 acc[4][4],
                                             int wm, int wn, int lo, int hi) {
#pragma unroll
  for (int kk = 0; kk < 2; ++kk) {
    bf16x8 a[4], bb[4];
#pragma unroll
    for (int i = 0; i < 4; ++i) {
      a[i]  = *(const bf16x8*)&As[(wm + i * 16 + lo) * 64 + kk * 32 + hi * 8];
      bb[i] = *(const bf16x8*)&Bs[(wn + i * 16 + lo) * 64 + kk * 32 + hi * 8];
    }
#pragma unroll
    for (int mi = 0; mi < 4; ++mi)
#pragma unroll
      for (int ni = 0; ni < 4; ++ni)
        acc[mi][ni] = MFMA16(a[mi], bb[ni], acc[mi][ni]);
  }
}

// EPI 0: bf16 store C[m*N+n]
// EPI 1: bf16 store C[(n>>6)*chunk + m*64 + (n&63)]   (batch-split columns)
// EPI 2: f32 store C[m*N+n] = acc + resid[m*N+n]
template <int EPI>
__device__ void gemm_body(const u16* __restrict__ A, const u16* __restrict__ Bm,
                          void* __restrict__ Cc, const float* __restrict__ resid,
                          int N, int K, int chunkStride, int mt, int nt, u16* lds) {
  int t = threadIdx.x, lane = t & 63, wv = t >> 6;
  int wm = (wv >> 1) * 64, wn = (wv & 1) * 64;
  int lo = lane & 15, hi = lane >> 4;
  f32x4 acc[4][4] = {};
  const u16* Ab = A + (size_t)mt * 128 * K;
  const u16* Bb = Bm + (size_t)nt * 128 * K;
  int nk = K >> 6;  // always even (16 or 64)
  u16* As0 = lds;          u16* Bs0 = lds + 8192;
  u16* As1 = lds + 16384;  u16* Bs1 = lds + 24576;
  stage_tile(Ab, Bb, K, 0, As0, Bs0, wv, lane);
  __syncthreads();
  for (int kt = 0; kt < nk; kt += 2) {
    stage_tile(Ab, Bb, K, kt + 1, As1, Bs1, wv, lane);
    compute_tile(As0, Bs0, acc, wm, wn, lo, hi);
    __syncthreads();
    if (kt + 2 < nk) stage_tile(Ab, Bb, K, kt + 2, As0, Bs0, wv, lane);
    compute_tile(As1, Bs1, acc, wm, wn, lo, hi);
    __syncthreads();
  }
#pragma unroll
  for (int mi = 0; mi < 4; ++mi)
#pragma unroll
    for (int ni = 0; ni < 4; ++ni)
#pragma unroll
      for (int r = 0; r < 4; ++r) {
        int m = mt * 128 + wm + mi * 16 + hi * 4 + r;
        int n = nt * 128 + wn + ni * 16 + lo;
        float v = acc[mi][ni][r];
        if constexpr (EPI == 0) {
          ((u16*)Cc)[(size_t)m * N + n] = f2bf(v);
        } else if constexpr (EPI == 1) {
          ((u16*)Cc)[(size_t)(n >> 6) * chunkStride + (size_t)m * 64 + (n & 63)] = f2bf(v);
        } else {
          size_t ad = (size_t)m * N + n;
          ((float*)Cc)[ad] = v + resid[ad];
        }
      }
}

template <int EPI>
__global__ __launch_bounds__(256) void gemm_kernel(const u16* __restrict__ A, const u16* __restrict__ Bm,
                                                   void* __restrict__ Cc, const float* __restrict__ resid,
                                                   int N, int K, int chunkStride) {
  __shared__ __align__(16) u16 lds[32768];
  int ntn = N >> 7;
  gemm_body<EPI>(A, Bm, Cc, resid, N, K, chunkStride, blockIdx.x / ntn, blockIdx.x % ntn, lds);
}

// fused Q + K + V projections (mutually independent): 256 + 64 + 64 blocks
__global__ __launch_bounds__(256) void qkv_kernel(
    const u16* __restrict__ Wt_q, const u16* __restrict__ xfT, u16* __restrict__ q_t,
    const u16* __restrict__ Wt_k, const u16* __restrict__ k_lnT, u16* __restrict__ kproj,
    const u16* __restrict__ v_lnT, const u16* __restrict__ Wt_v, u16* __restrict__ vproj) {
  __shared__ __align__(16) u16 lds[32768];
  int bid = blockIdx.x;
  if (bid < 256) {
    gemm_body<1>(Wt_q, xfT, q_t, nullptr, 1024, 4096, 4096 * 64, bid >> 3, bid & 7, lds);
  } else if (bid < 320) {
    int id = bid - 256;
    gemm_body<1>(Wt_k, k_lnT, kproj, nullptr, 1024, 1024, 1024 * 64, id >> 3, id & 7, lds);
  } else {
    int id = bid - 320;
    gemm_body<0>(v_lnT, Wt_v, vproj, nullptr, 1024, 1024, 0, id >> 3, id & 7, lds);
  }
}

// ================= attention: per (b, head, 128-row q tile); full K (128) per block =================
__global__ __launch_bounds__(256) void attn_kernel(const u16* __restrict__ q, const u16* __restrict__ kp,
                                                   const u16* __restrict__ vp, u16* __restrict__ o2) {
  __shared__ __align__(16) u16 Qs[128 * 72];
  __shared__ __align__(16) u16 Ks[128 * 72];
  __shared__ __align__(16) u16 Vs[64 * 136];
  __shared__ __align__(16) u16 Ps[128 * 136];
  int qt = blockIdx.x & 3, h = (blockIdx.x >> 2) & 7, b = blockIdx.x >> 5;
  int t = threadIdx.x, lane = t & 63, wv = t >> 6;
  int lo = lane & 15, hi = lane >> 4;
  const u16* qsrc = q + (size_t)b * 4096 * 64 + (size_t)(h * 512 + qt * 128) * 64;
  const u16* ksrc = kp + (size_t)b * 1024 * 64 + (size_t)(h * 128) * 64;
  const u16* vsrc = vp + (size_t)b * 64 * 1024 + h * 128;
#pragma unroll
  for (int i = 0; i < 4; ++i) {
    int id = t + i * 256;
    int row = id >> 3, c16 = id & 7;
    *(u32x4*)&Qs[row * 72 + c16 * 8] = *(const u32x4*)&qsrc[(size_t)row * 64 + c16 * 8];
    *(u32x4*)&Ks[row * 72 + c16 * 8] = *(const u32x4*)&ksrc[(size_t)row * 64 + c16 * 8];
    int vrow = id >> 4, v16 = id & 15;
    *(u32x4*)&Vs[vrow * 136 + v16 * 8] = *(const u32x4*)&vsrc[(size_t)vrow * 1024 + v16 * 8];
  }
  __syncthreads();
  // S = Q K^T : each wave owns 32 q-rows x 128 k-cols
  f32x4 s[2][8] = {};
#pragma unroll
  for (int kk = 0; kk < 2; ++kk) {
    bf16x8 a0 = *(const bf16x8*)&Qs[(wv * 32 + lo) * 72 + kk * 32 + hi * 8];
    bf16x8 a1 = *(const bf16x8*)&Qs[(wv * 32 + 16 + lo) * 72 + kk * 32 + hi * 8];
#pragma unroll
    for (int ni = 0; ni < 8; ++ni) {
      bf16x8 bb = *(const bf16x8*)&Ks[(ni * 16 + lo) * 72 + kk * 32 + hi * 8];
      s[0][ni] = MFMA16(a0, bb, s[0][ni]);
      s[1][ni] = MFMA16(a1, bb, s[1][ni]);
    }
  }
  const float inv_scale = 0.044194173824159216f;  // 1/sqrt(512)
#pragma unroll
  for (int mi = 0; mi < 2; ++mi)
#pragma unroll
    for (int ni = 0; ni < 8; ++ni) s[mi][ni] *= inv_scale;
#pragma unroll
  for (int mi = 0; mi < 2; ++mi) {
#pragma unroll
    for (int r = 0; r < 4; ++r) {
      float mx = -1e30f;
#pragma unroll
      for (int ni = 0; ni < 8; ++ni) mx = fmaxf(mx, s[mi][ni][r]);
#pragma unroll
      for (int m = 1; m < 16; m <<= 1) mx = fmaxf(mx, __shfl_xor(mx, m));
      float p[8], sum = 0.f;
#pragma unroll
      for (int ni = 0; ni < 8; ++ni) { p[ni] = __expf(s[mi][ni][r] - mx); sum += p[ni]; }
#pragma unroll
      for (int m = 1; m < 16; m <<= 1) sum += __shfl_xor(sum, m);
      float rs = 1.0f / sum;
      int row = wv * 32 + mi * 16 + hi * 4 + r;
#pragma unroll
      for (int ni = 0; ni < 8; ++ni) Ps[row * 136 + ni * 16 + lo] = f2bf(p[ni] * rs);
    }
  }
  __syncthreads();
  // O^T[c][lq] = sum_lk V[c][lk] * P[lq][lk] : each wave owns 64 c-rows x 32 lq-cols
  f32x4 o[4][2] = {};
#pragma unroll
  for (int kk = 0; kk < 4; ++kk) {
    bf16x8 b0 = *(const bf16x8*)&Ps[(wv * 32 + lo) * 136 + kk * 32 + hi * 8];
    bf16x8 b1 = *(const bf16x8*)&Ps[(wv * 32 + 16 + lo) * 136 + kk * 32 + hi * 8];
#pragma unroll
    for (int mi = 0; mi < 4; ++mi) {
      bf16x8 a = *(const bf16x8*)&Vs[(mi * 16 + lo) * 136 + kk * 32 + hi * 8];
      o[mi][0] = MFMA16(a, b0, o[mi][0]);
      o[mi][1] = MFMA16(a, b1, o[mi][1]);
    }
  }
  u16* od = o2 + (size_t)b * 64 * 4096 + h * 512 + qt * 128;
#pragma unroll
  for (int mi = 0; mi < 4; ++mi)
#pragma unroll
    for (int ni = 0; ni < 2; ++ni)
#pragma unroll
      for (int r = 0; r < 4; ++r) {
        int c = mi * 16 + hi * 4 + r;
        int lq = wv * 32 + ni * 16 + lo;
        od[(size_t)c * 4096 + lq] = f2bf(o[mi][ni][r]);
      }
}

extern "C" void kernel_launch(void* const* d_in, const int* in_sizes, int n_in,
                              void* d_out, int out_size, void* d_ws, size_t ws_size,
                              hipStream_t stream) {
  (void)in_sizes; (void)n_in; (void)out_size; (void)ws_size;
  const float* x    = (const float*)d_in[0];
  const float* ln1w = (const float*)d_in[1];
  const float* ln1b = (const float*)d_in[2];
  const float* ln2w = (const float*)d_in[3];
  const float* ln2b = (const float*)d_in[4];
  const float* W_rk = (const float*)d_in[5];
  const float* W_rv = (const float*)d_in[6];
  const float* W_q  = (const float*)d_in[7];
  const float* W_k  = (const float*)d_in[8];
  const float* W_v  = (const float*)d_in[9];
  const float* W_o  = (const float*)d_in[10];

  char* ws = (char*)d_ws;
  size_t off = 0;
  auto alloc = [&](size_t bytes) { char* p = ws + off; off += bytes; return p; };
  u16* Wt_q  = (u16*)alloc(4096ull * 4096 * 2);
  u16* Wt_o  = (u16*)alloc(4096ull * 4096 * 2);
  u16* Wt_k  = (u16*)alloc(1024ull * 1024 * 2);
  u16* Wt_v  = (u16*)alloc(1024ull * 1024 * 2);
  u16* Wt_rk = (u16*)alloc(64ull * 256 * 2);
  u16* Wt_rv = (u16*)alloc(64ull * 256 * 2);
  u16* xf_pc = (u16*)alloc(16ull * 4096 * 64 * 2);
  u16* xfT   = (u16*)alloc(16ull * 64 * 4096 * 2);
  u16* k_lnT = (u16*)alloc(16ull * 64 * 1024 * 2);
  u16* v_lnT = (u16*)alloc(16ull * 64 * 1024 * 2);
  u16* q_t   = (u16*)alloc(16ull * 4096 * 64 * 2);
  u16* kproj = (u16*)alloc(16ull * 1024 * 64 * 2);
  u16* vproj = (u16*)alloc(16ull * 64 * 1024 * 2);
  u16* o2    = (u16*)alloc(16ull * 64 * 4096 * 2);

  prep_kernel<<<9792, 256, 0, stream>>>(W_q, Wt_q, W_o, Wt_o, W_k, Wt_k, W_v, Wt_v,
                                        W_rk, W_rv, Wt_rk, Wt_rv, x, ln1w, ln1b, xf_pc, xfT);
  kv_kernel<<<256, 256, 0, stream>>>(xf_pc, Wt_rk, Wt_rv, ln2w, ln2b, k_lnT, v_lnT);
  // Q: q_t[b][j][c] = sum_p Wt_q[j][p]*xfT[(b,c)][p];  K: kproj[b][jk][c];  V: vproj[(b,c)][jv]
  qkv_kernel<<<384, 256, 0, stream>>>(Wt_q, xfT, q_t, Wt_k, k_lnT, kproj, v_lnT, Wt_v, vproj);
  attn_kernel<<<512, 256, 0, stream>>>(q_t, kproj, vproj, o2);
  // O: out[(b,c)][j2] = sum_j o2[(b,c)][j] * Wt_o[j2][j] + x
  gemm_kernel<2><<<256, 256, 0, stream>>>(o2, Wt_o, (float*)d_out, x, 4096, 4096, 0);
}

// Round 3
// 204.176 us; speedup vs baseline: 1.3377x; 1.0335x over previous
//
#include <hip/hip_runtime.h>

typedef unsigned short u16;
typedef unsigned int u32;
typedef __attribute__((ext_vector_type(8))) __bf16 bf16x8;
typedef __attribute__((ext_vector_type(4))) float f32x4;
typedef __attribute__((ext_vector_type(4))) unsigned int u32x4;

#define MFMA16(a, b, c) __builtin_amdgcn_mfma_f32_16x16x32_bf16((a), (b), (c), 0, 0, 0)

__device__ __forceinline__ u16 f2bf(float f) {
  unsigned u = __float_as_uint(f);
  u += 0x7FFFu + ((u >> 16) & 1u);
  return (u16)(u >> 16);
}

typedef __attribute__((address_space(1))) const unsigned char gU8;
typedef __attribute__((address_space(3))) unsigned char sU8;
__device__ __forceinline__ void gload16(const void* g, void* l) {
  __builtin_amdgcn_global_load_lds((gU8*)g, (sU8*)l, 16, 0, 0);
}

// ================= fused pre-pass: weight transposes + wperm + LN1 (16B/lane both ways) =================
__device__ __forceinline__ void wt_body(const float* __restrict__ W, u16* __restrict__ Wt,
                                        int K, int N, int bid, float* tile) {
  int ntn = N >> 6;
  int kt = bid / ntn, nt = bid % ntn;
  int t = threadIdx.x;
  const float* src = W + (size_t)kt * 64 * N + (size_t)nt * 64;
  // load 64x64 f32 tile, float4 per thread
#pragma unroll
  for (int i = 0; i < 4; ++i) {
    int idx = t + i * 256, row = idx >> 4, c4 = idx & 15;
    f32x4 v = *(const f32x4*)&src[(size_t)row * N + c4 * 4];
#pragma unroll
    for (int j = 0; j < 4; ++j) tile[row * 65 + c4 * 4 + j] = v[j];
  }
  __syncthreads();
  // store transposed: 8 bf16 (16B) per thread per iter
  u16* dst = Wt + (size_t)nt * 64 * K + (size_t)kt * 64;
#pragma unroll
  for (int i = 0; i < 2; ++i) {
    int idx = t + i * 256, nn = idx >> 3, k8 = idx & 7;
    u16 o[8];
#pragma unroll
    for (int j = 0; j < 8; ++j) o[j] = f2bf(tile[(k8 * 8 + j) * 65 + nn]);
    u32x4 pk;
#pragma unroll
    for (int j = 0; j < 4; ++j) pk[j] = (u32)o[2 * j] | ((u32)o[2 * j + 1] << 16);
    *(u32x4*)&dst[(size_t)nn * K + k8 * 8] = pk;
  }
}

__device__ __forceinline__ void wperm_body(const float* __restrict__ Wrk, const float* __restrict__ Wrv,
                                           u16* __restrict__ Wtk, u16* __restrict__ Wtv, int bid) {
  int idx = bid * 256 + threadIdx.x;  // 16384 = 64 c' * 256 f
  int cp = idx >> 8, f = idx & 255;
  int k = ((f & 63) << 2) | (f >> 6);
  Wtk[idx] = f2bf(Wrk[k * 64 + cp]);
  Wtv[idx] = f2bf(Wrv[k * 64 + cp]);
}

__device__ __forceinline__ void ln1_body(const float* __restrict__ x, const float* __restrict__ w,
                                         const float* __restrict__ bias, u16* __restrict__ xf_pc,
                                         u16* __restrict__ xfT, int bid, float* tile) {
  int b = bid >> 6, p0 = (bid & 63) << 6;
  int t = threadIdx.x;
  const float* xb = x + (size_t)b * 64 * 4096;
  // load 64 channels x 64 pixels, float4 per thread
#pragma unroll
  for (int i = 0; i < 4; ++i) {
    int idx = t + i * 256, c = idx >> 4, p4 = idx & 15;
    f32x4 v = *(const f32x4*)&xb[(size_t)c * 4096 + p0 + p4 * 4];
#pragma unroll
    for (int j = 0; j < 4; ++j) tile[c * 65 + p4 * 4 + j] = v[j];
  }
  __syncthreads();
  int lane = t & 63, wv = t >> 6;
  float gw = w[lane], gb = bias[lane];
  for (int pi = 0; pi < 16; ++pi) {
    int p = wv * 16 + pi;
    float v = tile[lane * 65 + p];
    float s = v, s2 = v * v;
#pragma unroll
    for (int m = 1; m < 64; m <<= 1) { s += __shfl_xor(s, m); s2 += __shfl_xor(s2, m); }
    float mean = s * (1.0f / 64.0f);
    float var = s2 * (1.0f / 64.0f) - mean * mean;
    float y = (v - mean) * rsqrtf(var + 1e-5f) * gw + gb;
    tile[lane * 65 + p] = y;
  }
  __syncthreads();
  u16* xfb = xf_pc + (size_t)b * 4096 * 64;
  u16* xtb = xfT + (size_t)b * 64 * 4096;
  // xf_pc[p][c]: column reads, vec8 store
#pragma unroll
  for (int i = 0; i < 2; ++i) {
    int idx = t + i * 256, p = idx >> 3, c8 = idx & 7;
    u16 o[8];
#pragma unroll
    for (int j = 0; j < 8; ++j) o[j] = f2bf(tile[(c8 * 8 + j) * 65 + p]);
    u32x4 pk;
#pragma unroll
    for (int j = 0; j < 4; ++j) pk[j] = (u32)o[2 * j] | ((u32)o[2 * j + 1] << 16);
    *(u32x4*)&xfb[(size_t)(p0 + p) * 64 + c8 * 8] = pk;
  }
  // xfT[c][p]: row reads, vec8 store
#pragma unroll
  for (int i = 0; i < 2; ++i) {
    int idx = t + i * 256, c = idx >> 3, p8 = idx & 7;
    u16 o[8];
#pragma unroll
    for (int j = 0; j < 8; ++j) o[j] = f2bf(tile[c * 65 + p8 * 8 + j]);
    u32x4 pk;
#pragma unroll
    for (int j = 0; j < 4; ++j) pk[j] = (u32)o[2 * j] | ((u32)o[2 * j + 1] << 16);
    *(u32x4*)&xtb[(size_t)c * 4096 + p0 + p8 * 8] = pk;
  }
}

__global__ __launch_bounds__(256) void prep_kernel(
    const float* __restrict__ W_q, u16* __restrict__ Wt_q,
    const float* __restrict__ W_o, u16* __restrict__ Wt_o,
    const float* __restrict__ W_k, u16* __restrict__ Wt_k,
    const float* __restrict__ W_v, u16* __restrict__ Wt_v,
    const float* __restrict__ W_rk, const float* __restrict__ W_rv,
    u16* __restrict__ Wt_rk, u16* __restrict__ Wt_rv,
    const float* __restrict__ x, const float* __restrict__ ln1w, const float* __restrict__ ln1b,
    u16* __restrict__ xf_pc, u16* __restrict__ xfT) {
  __shared__ float tile[64 * 65];
  int bid = blockIdx.x;
  if (bid < 4096)       wt_body(W_q, Wt_q, 4096, 4096, bid, tile);
  else if (bid < 8192)  wt_body(W_o, Wt_o, 4096, 4096, bid - 4096, tile);
  else if (bid < 8448)  wt_body(W_k, Wt_k, 1024, 1024, bid - 8192, tile);
  else if (bid < 8704)  wt_body(W_v, Wt_v, 1024, 1024, bid - 8448, tile);
  else if (bid < 8768)  wperm_body(W_rk, W_rv, Wt_rk, Wt_rv, bid - 8704);
  else                  ln1_body(x, ln1w, ln1b, xf_pc, xfT, bid - 8768, tile);
}

// ================= KV spatial reduction GEMM (64x64x256) + LN2 + transposed store =================
__global__ __launch_bounds__(256) void kv_kernel(const u16* __restrict__ xf_pc,
                                                 const u16* __restrict__ Wtk, const u16* __restrict__ Wtv,
                                                 const float* __restrict__ ln2w, const float* __restrict__ ln2b,
                                                 u16* __restrict__ kT, u16* __restrict__ vT) {
  __shared__ __align__(16) u16 As[64 * 264];
  __shared__ __align__(16) u16 Bk[64 * 264];
  __shared__ __align__(16) u16 Bv[64 * 264];
  u16* Tk = As;            // reuse As after compute (needs 64*72)
  u16* Tv = As + 64 * 72;  // 2*64*72 = 9216 <= 64*264
  int b = blockIdx.x >> 4, s0 = (blockIdx.x & 15) << 6;
  int t = threadIdx.x;
  const u16* Asrc = xf_pc + (size_t)b * 4096 * 64 + (size_t)s0 * 256;
#pragma unroll
  for (int i = 0; i < 8; ++i) {
    int id = t + i * 256, row = id >> 5, c16 = id & 31;
    *(u32x4*)&As[row * 264 + c16 * 8] = *(const u32x4*)&Asrc[(size_t)row * 256 + c16 * 8];
    *(u32x4*)&Bk[row * 264 + c16 * 8] = *(const u32x4*)&Wtk[(size_t)row * 256 + c16 * 8];
    *(u32x4*)&Bv[row * 264 + c16 * 8] = *(const u32x4*)&Wtv[(size_t)row * 256 + c16 * 8];
  }
  __syncthreads();
  int lane = t & 63, wv = t >> 6, lo = lane & 15, hi = lane >> 4;
  f32x4 acck[4] = {}, accv[4] = {};
  int arow = (wv * 16 + lo) * 264 + hi * 8;
#pragma unroll
  for (int kk = 0; kk < 8; ++kk) {
    bf16x8 a = *(const bf16x8*)&As[arow + kk * 32];
#pragma unroll
    for (int nf = 0; nf < 4; ++nf) {
      bf16x8 bk = *(const bf16x8*)&Bk[(nf * 16 + lo) * 264 + kk * 32 + hi * 8];
      bf16x8 bv = *(const bf16x8*)&Bv[(nf * 16 + lo) * 264 + kk * 32 + hi * 8];
      acck[nf] = MFMA16(a, bk, acck[nf]);
      accv[nf] = MFMA16(a, bv, accv[nf]);
    }
  }
  __syncthreads();  // done reading As; Tk/Tv alias it
  float w2[4], b2[4];
#pragma unroll
  for (int nf = 0; nf < 4; ++nf) { w2[nf] = ln2w[nf * 16 + lo]; b2[nf] = ln2b[nf * 16 + lo]; }
#pragma unroll
  for (int r = 0; r < 4; ++r) {
    float sk = 0.f, sk2 = 0.f, sv = 0.f, sv2 = 0.f;
#pragma unroll
    for (int nf = 0; nf < 4; ++nf) {
      float a = acck[nf][r], c = accv[nf][r];
      sk += a; sk2 += a * a; sv += c; sv2 += c * c;
    }
#pragma unroll
    for (int m = 1; m < 16; m <<= 1) {
      sk += __shfl_xor(sk, m); sk2 += __shfl_xor(sk2, m);
      sv += __shfl_xor(sv, m); sv2 += __shfl_xor(sv2, m);
    }
    float mk = sk * (1.f / 64.f), vk = sk2 * (1.f / 64.f) - mk * mk, rk = rsqrtf(vk + 1e-5f);
    float mv = sv * (1.f / 64.f), vv = sv2 * (1.f / 64.f) - mv * mv, rv = rsqrtf(vv + 1e-5f);
    int srow = wv * 16 + hi * 4 + r;
#pragma unroll
    for (int nf = 0; nf < 4; ++nf) {
      Tk[(nf * 16 + lo) * 72 + srow] = f2bf((acck[nf][r] - mk) * rk * w2[nf] + b2[nf]);
      Tv[(nf * 16 + lo) * 72 + srow] = f2bf((accv[nf][r] - mv) * rv * w2[nf] + b2[nf]);
    }
  }
  __syncthreads();
  u16* kdst = kT + (size_t)b * 64 * 1024 + s0;
  u16* vdst = vT + (size_t)b * 64 * 1024 + s0;
#pragma unroll
  for (int i = 0; i < 16; ++i) {
    int idx = t + i * 256, cp = idx >> 6, s = idx & 63;
    kdst[(size_t)cp * 1024 + s] = Tk[cp * 72 + s];
    vdst[(size_t)cp * 1024 + s] = Tv[cp * 72 + s];
  }
}

// ================= GEMM body: gload_lds staging + double-buffered 2-phase =================
// C[m][n] = sum_k A[m][k]*B[n][k], tile 128x128x64, linear LDS (gload_lds requirement)
__device__ __forceinline__ void stage_tile(const u16* Ab, const u16* Bb, int K, int kt,
                                           u16* As, u16* Bs, int wv, int lane) {
  int gr = lane >> 3;              // row within 8-row chunk
  int gcol = (lane & 7) * 8;       // element col within 64
  const u16* a0 = Ab + (size_t)kt * 64 + gcol;
  const u16* b0 = Bb + (size_t)kt * 64 + gcol;
#pragma unroll
  for (int i = 0; i < 4; ++i) {
    int chunk = wv * 4 + i;
    int row = chunk * 8 + gr;
    gload16(a0 + (size_t)row * K, As + chunk * 512);
    gload16(b0 + (size_t)row * K, Bs + chunk * 512);
  }
}

__device__ __forceinline__ void compute_tile(const u16* As, const u16* Bs, f32x4 acc[4][4],
                                             int wm, int wn, int lo, int hi) {
#pragma unroll
  for (int kk = 0; kk < 2; ++kk) {
    bf16x8 a[4], bb[4];
#pragma unroll
    for (int i = 0; i < 4; ++i) {
      a[i]  = *(const bf16x8*)&As[(wm + i * 16 + lo) * 64 + kk * 32 + hi * 8];
      bb[i] = *(const bf16x8*)&Bs[(wn + i * 16 + lo) * 64 + kk * 32 + hi * 8];
    }
#pragma unroll
    for (int mi = 0; mi < 4; ++mi)
#pragma unroll
      for (int ni = 0; ni < 4; ++ni)
        acc[mi][ni] = MFMA16(a[mi], bb[ni], acc[mi][ni]);
  }
}

// EPI 0: bf16 store C[m*N+n]
// EPI 1: bf16 store C[(n>>6)*chunk + m*64 + (n&63)]   (batch-split columns)
// EPI 2: f32 store C[m*N+n] = acc + resid[m*N+n]
template <int EPI>
__device__ void gemm_body(const u16* __restrict__ A, const u16* __restrict__ Bm,
                          void* __restrict__ Cc, const float* __restrict__ resid,
                          int N, int K, int chunkStride, int mt, int nt, u16* lds) {
  int t = threadIdx.x, lane = t & 63, wv = t >> 6;
  int wm = (wv >> 1) * 64, wn = (wv & 1) * 64;
  int lo = lane & 15, hi = lane >> 4;
  f32x4 acc[4][4] = {};
  const u16* Ab = A + (size_t)mt * 128 * K;
  const u16* Bb = Bm + (size_t)nt * 128 * K;
  int nk = K >> 6;  // always even (16 or 64)
  u16* As0 = lds;          u16* Bs0 = lds + 8192;
  u16* As1 = lds + 16384;  u16* Bs1 = lds + 24576;
  stage_tile(Ab, Bb, K, 0, As0, Bs0, wv, lane);
  __syncthreads();
  for (int kt = 0; kt < nk; kt += 2) {
    stage_tile(Ab, Bb, K, kt + 1, As1, Bs1, wv, lane);
    compute_tile(As0, Bs0, acc, wm, wn, lo, hi);
    __syncthreads();
    if (kt + 2 < nk) stage_tile(Ab, Bb, K, kt + 2, As0, Bs0, wv, lane);
    compute_tile(As1, Bs1, acc, wm, wn, lo, hi);
    __syncthreads();
  }
#pragma unroll
  for (int mi = 0; mi < 4; ++mi)
#pragma unroll
    for (int ni = 0; ni < 4; ++ni)
#pragma unroll
      for (int r = 0; r < 4; ++r) {
        int m = mt * 128 + wm + mi * 16 + hi * 4 + r;
        int n = nt * 128 + wn + ni * 16 + lo;
        float v = acc[mi][ni][r];
        if constexpr (EPI == 0) {
          ((u16*)Cc)[(size_t)m * N + n] = f2bf(v);
        } else if constexpr (EPI == 1) {
          ((u16*)Cc)[(size_t)(n >> 6) * chunkStride + (size_t)m * 64 + (n & 63)] = f2bf(v);
        } else {
          size_t ad = (size_t)m * N + n;
          ((float*)Cc)[ad] = v + resid[ad];
        }
      }
}

template <int EPI>
__global__ __launch_bounds__(256) void gemm_kernel(const u16* __restrict__ A, const u16* __restrict__ Bm,
                                                   void* __restrict__ Cc, const float* __restrict__ resid,
                                                   int N, int K, int chunkStride) {
  __shared__ __align__(16) u16 lds[32768];
  int ntn = N >> 7;
  gemm_body<EPI>(A, Bm, Cc, resid, N, K, chunkStride, blockIdx.x / ntn, blockIdx.x % ntn, lds);
}

// fused Q + K + V projections (mutually independent): 256 + 64 + 64 blocks
__global__ __launch_bounds__(256) void qkv_kernel(
    const u16* __restrict__ Wt_q, const u16* __restrict__ xfT, u16* __restrict__ q_t,
    const u16* __restrict__ Wt_k, const u16* __restrict__ k_lnT, u16* __restrict__ kproj,
    const u16* __restrict__ v_lnT, const u16* __restrict__ Wt_v, u16* __restrict__ vproj) {
  __shared__ __align__(16) u16 lds[32768];
  int bid = blockIdx.x;
  if (bid < 256) {
    gemm_body<1>(Wt_q, xfT, q_t, nullptr, 1024, 4096, 4096 * 64, bid >> 3, bid & 7, lds);
  } else if (bid < 320) {
    int id = bid - 256;
    gemm_body<1>(Wt_k, k_lnT, kproj, nullptr, 1024, 1024, 1024 * 64, id >> 3, id & 7, lds);
  } else {
    int id = bid - 320;
    gemm_body<0>(v_lnT, Wt_v, vproj, nullptr, 1024, 1024, 0, id >> 3, id & 7, lds);
  }
}

// ================= attention: per (b, head, 128-row q tile); full K (128) per block =================
__global__ __launch_bounds__(256) void attn_kernel(const u16* __restrict__ q, const u16* __restrict__ kp,
                                                   const u16* __restrict__ vp, u16* __restrict__ o2) {
  __shared__ __align__(16) u16 Qs[128 * 72];
  __shared__ __align__(16) u16 Ks[128 * 72];
  __shared__ __align__(16) u16 Vs[64 * 136];
  __shared__ __align__(16) u16 Ps[128 * 136];
  int qt = blockIdx.x & 3, h = (blockIdx.x >> 2) & 7, b = blockIdx.x >> 5;
  int t = threadIdx.x, lane = t & 63, wv = t >> 6;
  int lo = lane & 15, hi = lane >> 4;
  const u16* qsrc = q + (size_t)b * 4096 * 64 + (size_t)(h * 512 + qt * 128) * 64;
  const u16* ksrc = kp + (size_t)b * 1024 * 64 + (size_t)(h * 128) * 64;
  const u16* vsrc = vp + (size_t)b * 64 * 1024 + h * 128;
#pragma unroll
  for (int i = 0; i < 4; ++i) {
    int id = t + i * 256;
    int row = id >> 3, c16 = id & 7;
    *(u32x4*)&Qs[row * 72 + c16 * 8] = *(const u32x4*)&qsrc[(size_t)row * 64 + c16 * 8];
    *(u32x4*)&Ks[row * 72 + c16 * 8] = *(const u32x4*)&ksrc[(size_t)row * 64 + c16 * 8];
    int vrow = id >> 4, v16 = id & 15;
    *(u32x4*)&Vs[vrow * 136 + v16 * 8] = *(const u32x4*)&vsrc[(size_t)vrow * 1024 + v16 * 8];
  }
  __syncthreads();
  // S = Q K^T : each wave owns 32 q-rows x 128 k-cols
  f32x4 s[2][8] = {};
#pragma unroll
  for (int kk = 0; kk < 2; ++kk) {
    bf16x8 a0 = *(const bf16x8*)&Qs[(wv * 32 + lo) * 72 + kk * 32 + hi * 8];
    bf16x8 a1 = *(const bf16x8*)&Qs[(wv * 32 + 16 + lo) * 72 + kk * 32 + hi * 8];
#pragma unroll
    for (int ni = 0; ni < 8; ++ni) {
      bf16x8 bb = *(const bf16x8*)&Ks[(ni * 16 + lo) * 72 + kk * 32 + hi * 8];
      s[0][ni] = MFMA16(a0, bb, s[0][ni]);
      s[1][ni] = MFMA16(a1, bb, s[1][ni]);
    }
  }
  const float inv_scale = 0.044194173824159216f;  // 1/sqrt(512)
#pragma unroll
  for (int mi = 0; mi < 2; ++mi)
#pragma unroll
    for (int ni = 0; ni < 8; ++ni) s[mi][ni] *= inv_scale;
#pragma unroll
  for (int mi = 0; mi < 2; ++mi) {
#pragma unroll
    for (int r = 0; r < 4; ++r) {
      float mx = -1e30f;
#pragma unroll
      for (int ni = 0; ni < 8; ++ni) mx = fmaxf(mx, s[mi][ni][r]);
#pragma unroll
      for (int m = 1; m < 16; m <<= 1) mx = fmaxf(mx, __shfl_xor(mx, m));
      float p[8], sum = 0.f;
#pragma unroll
      for (int ni = 0; ni < 8; ++ni) { p[ni] = __expf(s[mi][ni][r] - mx); sum += p[ni]; }
#pragma unroll
      for (int m = 1; m < 16; m <<= 1) sum += __shfl_xor(sum, m);
      float rs = 1.0f / sum;
      int row = wv * 32 + mi * 16 + hi * 4 + r;
#pragma unroll
      for (int ni = 0; ni < 8; ++ni) Ps[row * 136 + ni * 16 + lo] = f2bf(p[ni] * rs);
    }
  }
  __syncthreads();
  // O^T[c][lq] = sum_lk V[c][lk] * P[lq][lk] : each wave owns 64 c-rows x 32 lq-cols
  f32x4 o[4][2] = {};
#pragma unroll
  for (int kk = 0; kk < 4; ++kk) {
    bf16x8 b0 = *(const bf16x8*)&Ps[(wv * 32 + lo) * 136 + kk * 32 + hi * 8];
    bf16x8 b1 = *(const bf16x8*)&Ps[(wv * 32 + 16 + lo) * 136 + kk * 32 + hi * 8];
#pragma unroll
    for (int mi = 0; mi < 4; ++mi) {
      bf16x8 a = *(const bf16x8*)&Vs[(mi * 16 + lo) * 136 + kk * 32 + hi * 8];
      o[mi][0] = MFMA16(a, b0, o[mi][0]);
      o[mi][1] = MFMA16(a, b1, o[mi][1]);
    }
  }
  u16* od = o2 + (size_t)b * 64 * 4096 + h * 512 + qt * 128;
#pragma unroll
  for (int mi = 0; mi < 4; ++mi)
#pragma unroll
    for (int ni = 0; ni < 2; ++ni)
#pragma unroll
      for (int r = 0; r < 4; ++r) {
        int c = mi * 16 + hi * 4 + r;
        int lq = wv * 32 + ni * 16 + lo;
        od[(size_t)c * 4096 + lq] = f2bf(o[mi][ni][r]);
      }
}

extern "C" void kernel_launch(void* const* d_in, const int* in_sizes, int n_in,
                              void* d_out, int out_size, void* d_ws, size_t ws_size,
                              hipStream_t stream) {
  (void)in_sizes; (void)n_in; (void)out_size; (void)ws_size;
  const float* x    = (const float*)d_in[0];
  const float* ln1w = (const float*)d_in[1];
  const float* ln1b = (const float*)d_in[2];
  const float* ln2w = (const float*)d_in[3];
  const float* ln2b = (const float*)d_in[4];
  const float* W_rk = (const float*)d_in[5];
  const float* W_rv = (const float*)d_in[6];
  const float* W_q  = (const float*)d_in[7];
  const float* W_k  = (const float*)d_in[8];
  const float* W_v  = (const float*)d_in[9];
  const float* W_o  = (const float*)d_in[10];

  char* ws = (char*)d_ws;
  size_t off = 0;
  auto alloc = [&](size_t bytes) { char* p = ws + off; off += bytes; return p; };
  u16* Wt_q  = (u16*)alloc(4096ull * 4096 * 2);
  u16* Wt_o  = (u16*)alloc(4096ull * 4096 * 2);
  u16* Wt_k  = (u16*)alloc(1024ull * 1024 * 2);
  u16* Wt_v  = (u16*)alloc(1024ull * 1024 * 2);
  u16* Wt_rk = (u16*)alloc(64ull * 256 * 2);
  u16* Wt_rv = (u16*)alloc(64ull * 256 * 2);
  u16* xf_pc = (u16*)alloc(16ull * 4096 * 64 * 2);
  u16* xfT   = (u16*)alloc(16ull * 64 * 4096 * 2);
  u16* k_lnT = (u16*)alloc(16ull * 64 * 1024 * 2);
  u16* v_lnT = (u16*)alloc(16ull * 64 * 1024 * 2);
  u16* q_t   = (u16*)alloc(16ull * 4096 * 64 * 2);
  u16* kproj = (u16*)alloc(16ull * 1024 * 64 * 2);
  u16* vproj = (u16*)alloc(16ull * 64 * 1024 * 2);
  u16* o2    = (u16*)alloc(16ull * 64 * 4096 * 2);

  prep_kernel<<<9792, 256, 0, stream>>>(W_q, Wt_q, W_o, Wt_o, W_k, Wt_k, W_v, Wt_v,
                                        W_rk, W_rv, Wt_rk, Wt_rv, x, ln1w, ln1b, xf_pc, xfT);
  kv_kernel<<<256, 256, 0, stream>>>(xf_pc, Wt_rk, Wt_rv, ln2w, ln2b, k_lnT, v_lnT);
  // Q: q_t[b][j][c] = sum_p Wt_q[j][p]*xfT[(b,c)][p];  K: kproj[b][jk][c];  V: vproj[(b,c)][jv]
  qkv_kernel<<<384, 256, 0, stream>>>(Wt_q, xfT, q_t, Wt_k, k_lnT, kproj, v_lnT, Wt_v, vproj);
  attn_kernel<<<512, 256, 0, stream>>>(q_t, kproj, vproj, o2);
  // O: out[(b,c)][j2] = sum_j o2[(b,c)][j] * Wt_o[j2][j] + x
  gemm_kernel<2><<<256, 256, 0, stream>>>(o2, Wt_o, (float*)d_out, x, 4096, 4096, 0);
}